// Round 7
// baseline (5527.444 us; speedup 1.0000x reference)
//
#include <hip/hip_runtime.h>

#define NB 64
#define NS 256
#define ND 2048
#define NH 16
#define NHD 128

typedef unsigned short ushort_t;
typedef __attribute__((ext_vector_type(8))) __bf16 bf16x8;
typedef __attribute__((ext_vector_type(4))) short shortx4;
typedef __attribute__((ext_vector_type(4))) float f32x4;
typedef __attribute__((ext_vector_type(4))) unsigned short ushortx4;

__device__ __forceinline__ unsigned short f2bf(float f) {
  union { float f; unsigned int u; } v; v.f = f;
  unsigned int r = v.u + 0x7FFFu + ((v.u >> 16) & 1u);
  return (unsigned short)(r >> 16);
}

__device__ __forceinline__ void gload16(const void* g, void* l) {
  __builtin_amdgcn_global_load_lds(
      (__attribute__((address_space(1))) void*)(void*)(g),
      (__attribute__((address_space(3))) void*)(l), 16, 0, 0);
}

__global__ void cast_f32_bf16(const float* __restrict__ in, ushort_t* __restrict__ out, long n) {
  long i = ((long)blockIdx.x * blockDim.x + threadIdx.x) * 4;
  if (i + 3 < n) {
    float4 v = *reinterpret_cast<const float4*>(in + i);
    ushortx4 o;
    o.x = f2bf(v.x); o.y = f2bf(v.y); o.z = f2bf(v.z); o.w = f2bf(v.w);
    *reinterpret_cast<ushortx4*>(out + i) = o;
  }
}

// ---------------------------------------------------------------------------
// 256x256 tile GEMM, BK=32, 8 waves (2M x 4N).
// Round-6 change: 2-buffer double-buffer (64 KiB LDS) + __launch_bounds__(512,4)
// so TWO blocks co-reside per CU (was 4-buf/128KiB -> 1 block/CU, occupancy
// 22.6%). Rounds 1-5 showed the intra-block schedule family plateaus at
// MfmaUtil ~47% because a single barrier-locked block serializes the LDS and
// MFMA pipes; cross-block overlap (m114 mechanism) hides one block's
// stage/read/wait phases under the other's MFMA cluster with no source-level
// choreography. Simple 2-phase schedule per tile:
//   stage(t+1) -> buf^1 (issued FIRST: HBM latency hides under reads+MFMA);
//   ds_read 12 frags of tile t; lgkmcnt(0); setprio(1); 32 MFMA; setprio(0);
//   vmcnt(0); barrier.
// T2 XOR swizzle (inverse-swizzled global source, swizzled ds_read, linear
// gload_lds dest), T1 bijective XCD swizzle unchanged; bank conflicts = 0.
// C[m,n] = sum_k A[m,k]*Bt[n,k].  MODE 0: fp32 C.  MODE 1: bf16 permuted qkv.
// ---------------------------------------------------------------------------
template<int MODE>
__global__ __launch_bounds__(512, 4) void gemm256(const ushort_t* __restrict__ A,
                                                  const ushort_t* __restrict__ Bt,
                                                  float* __restrict__ Cf,
                                                  ushort_t* __restrict__ Cq,
                                                  int M, int N, int K) {
  extern __shared__ char smem[];   // 2 bufs * 32768B; A at +0 (16KB), B at +16384
  const int tid = threadIdx.x;
  const int wv = tid >> 6, lane = tid & 63;
  const int l15 = lane & 15, lg = lane >> 4;
  const int wm = wv >> 2, wn = wv & 3;     // 2 x 4 wave grid; wave tile 128x64

  // T1: bijective XCD-aware block swizzle
  const int nbn = N >> 8;
  const int nwg = (M >> 8) * nbn;
  const int bid = blockIdx.x;
  const int q8 = nwg >> 3, r8 = nwg & 7;
  const int xcd = bid & 7, lin = bid >> 3;
  const int wg = (xcd < r8 ? xcd * (q8 + 1) : r8 * (q8 + 1) + (xcd - r8) * q8) + lin;
  const int m0 = (wg / nbn) << 8;
  const int n0 = (wg % nbn) << 8;

  // staging source (per-lane, pre-swizzled; LDS dest stays linear)
  const int srow = wv * 16 + (lane >> 2);
  const int sce = ((lane & 3) * 8) ^ (((srow >> 1) & 3) << 3);  // elems
  const ushort_t* pa0 = A  + (long)(m0 + srow) * K + sce;        // rows 0..127
  const ushort_t* pa1 = pa0 + (long)128 * K;                     // rows 128..255
  const ushort_t* pb0 = Bt + (long)(n0 + srow) * K + sce;
  const ushort_t* pb1 = pb0 + (long)128 * K;

  // ds_read byte-XOR constant
  const int c = (lg * 16) ^ (((l15 >> 1) & 3) << 4);

  f32x4 acc[8][4] = {};
  const int nkt = K >> 5;

  // prologue: stage tile 0 -> buf0
  {
    char* d = smem + wv * 1024;
    gload16(pa0, d);
    gload16(pa1, d + 8192);
    gload16(pb0, d + 16384);
    gload16(pb1, d + 24576);
  }
  asm volatile("s_waitcnt vmcnt(0)" ::: "memory");
  __builtin_amdgcn_s_barrier();

  for (int t = 0; t < nkt; ++t) {
    const char* rb = smem + (t & 1) * 32768;
    // stage next tile first: HBM latency overlaps the reads + MFMA below
    if (t + 1 < nkt) {
      char* d = smem + ((t + 1) & 1) * 32768 + wv * 1024;
      const long ko = (long)(t + 1) * 32;
      gload16(pa0 + ko, d);
      gload16(pa1 + ko, d + 8192);
      gload16(pb0 + ko, d + 16384);
      gload16(pb1 + ko, d + 24576);
    }
    bf16x8 af[8], bfr[4];
    #pragma unroll
    for (int i = 0; i < 8; ++i)
      af[i] = *reinterpret_cast<const bf16x8*>(rb + (wm * 128 + i * 16 + l15) * 64 + c);
    #pragma unroll
    for (int j = 0; j < 4; ++j)
      bfr[j] = *reinterpret_cast<const bf16x8*>(rb + 16384 + (wn * 64 + j * 16 + l15) * 64 + c);
    asm volatile("s_waitcnt lgkmcnt(0)" ::: "memory");
    __builtin_amdgcn_sched_barrier(0);
    __builtin_amdgcn_s_setprio(1);
    #pragma unroll
    for (int i = 0; i < 8; ++i)
      #pragma unroll
      for (int j = 0; j < 4; ++j)
        acc[i][j] = __builtin_amdgcn_mfma_f32_16x16x32_bf16(af[i], bfr[j], acc[i][j], 0, 0, 0);
    __builtin_amdgcn_s_setprio(0);
    __builtin_amdgcn_sched_barrier(0);
    asm volatile("s_waitcnt vmcnt(0)" ::: "memory");  // next-tile stage landed
    __builtin_amdgcn_s_barrier();
  }

  // epilogue: D frag col = l15 (n), rows = lg*4 + r
  #pragma unroll
  for (int k = 0; k < 8; ++k) {
    const int mrow = m0 + wm * 128 + k * 16 + lg * 4;
    #pragma unroll
    for (int j = 0; j < 4; ++j) {
      const int n = n0 + wn * 64 + j * 16 + l15;
      #pragma unroll
      for (int r = 0; r < 4; ++r) {
        const int m = mrow + r;
        const float v = acc[k][j][r];
        if (MODE == 0) {
          Cf[(long)m * N + n] = v;
        } else {
          const int tq = n >> 11, hh = (n >> 7) & 15, hd = n & 127;
          const int b = m >> 8, s = m & 255;
          Cq[((((long)tq * NB + b) * NH + hh) * NS + s) * NHD + hd] = f2bf(v);
        }
      }
    }
  }
}

// One block per (b,h); 8 waves x 32 Q-rows. Flash-style online softmax.
// (Round-5 version restored: the round-6 "balanced" variant + transpose_v
// regressed total by 148us — fixed per-iteration costs dominate at S=256.)
__global__ __launch_bounds__(512) void attn_fused(const ushort_t* __restrict__ qkv,
                                                  ushort_t* __restrict__ ctx) {
  const int bh = blockIdx.x;
  const int b = bh >> 4, h = bh & 15;
  const int wave = threadIdx.x >> 6, lane = threadIdx.x & 63;
  const int l15 = lane & 15, lg = lane >> 4;
  const long head_off = ((long)(b * NH + h)) * (NS * NHD);
  const ushort_t* Qp = qkv + head_off;
  const ushort_t* Kp = qkv + (long)NB * NH * NS * NHD + head_off;
  const ushort_t* Vp = qkv + 2L * NB * NH * NS * NHD + head_off;
  const int q0 = wave * 32;

  bf16x8 qf[2][4];
  #pragma unroll
  for (int ni = 0; ni < 2; ++ni)
    #pragma unroll
    for (int kk = 0; kk < 4; ++kk)
      qf[ni][kk] = *reinterpret_cast<const bf16x8*>(Qp + (q0 + ni * 16 + l15) * NHD + kk * 32 + lg * 8);

  f32x4 o[8][2] = {};
  float mstate[2] = {-1e30f, -1e30f};
  float lstate[2] = {0.f, 0.f};
  const float scale = 0.08838834764831845f;
  const int ntiles = (q0 + 32 + 63) >> 6;

  for (int kt = 0; kt < ntiles; ++kt) {
    f32x4 st[4][2] = {};
    #pragma unroll
    for (int kk = 0; kk < 4; ++kk) {
      bf16x8 kf[4];
      #pragma unroll
      for (int mi = 0; mi < 4; ++mi)
        kf[mi] = *reinterpret_cast<const bf16x8*>(Kp + (kt * 64 + mi * 16 + l15) * NHD + kk * 32 + lg * 8);
      #pragma unroll
      for (int mi = 0; mi < 4; ++mi)
        #pragma unroll
        for (int ni = 0; ni < 2; ++ni)
          st[mi][ni] = __builtin_amdgcn_mfma_f32_16x16x32_bf16(kf[mi], qf[ni][kk], st[mi][ni], 0, 0, 0);
    }
    const bool last = (kt == ntiles - 1);
    #pragma unroll
    for (int mi = 0; mi < 4; ++mi)
      #pragma unroll
      for (int ni = 0; ni < 2; ++ni)
        #pragma unroll
        for (int r = 0; r < 4; ++r) {
          const int kc = kt * 64 + mi * 16 + lg * 4 + r;
          const int q = q0 + ni * 16 + l15;
          float v = st[mi][ni][r] * scale;
          if (last && kc > q) v = -1e30f;
          st[mi][ni][r] = v;
        }
    shortx4 p[4][2];
    #pragma unroll
    for (int ni = 0; ni < 2; ++ni) {
      float tmax = -1e30f;
      #pragma unroll
      for (int mi = 0; mi < 4; ++mi)
        #pragma unroll
        for (int r = 0; r < 4; ++r) tmax = fmaxf(tmax, st[mi][ni][r]);
      tmax = fmaxf(tmax, __shfl_xor(tmax, 16, 64));
      tmax = fmaxf(tmax, __shfl_xor(tmax, 32, 64));
      const float mnew = fmaxf(mstate[ni], tmax);
      const float alpha = __expf(mstate[ni] - mnew);
      float tsum = 0.f;
      #pragma unroll
      for (int mi = 0; mi < 4; ++mi)
        #pragma unroll
        for (int r = 0; r < 4; ++r) {
          const float pe = __expf(st[mi][ni][r] - mnew);
          st[mi][ni][r] = pe;
          tsum += pe;
        }
      tsum += __shfl_xor(tsum, 16, 64);
      tsum += __shfl_xor(tsum, 32, 64);
      lstate[ni] = lstate[ni] * alpha + tsum;
      mstate[ni] = mnew;
      #pragma unroll
      for (int f = 0; f < 8; ++f)
        #pragma unroll
        for (int r = 0; r < 4; ++r) o[f][ni][r] *= alpha;
      #pragma unroll
      for (int mi = 0; mi < 4; ++mi)
        #pragma unroll
        for (int r = 0; r < 4; ++r) p[mi][ni][r] = (short)f2bf(st[mi][ni][r]);
    }
    #pragma unroll
    for (int f = 0; f < 8; ++f)
      #pragma unroll
      for (int mi = 0; mi < 4; ++mi) {
        shortx4 vt;
        #pragma unroll
        for (int j = 0; j < 4; ++j)
          vt[j] = (short)Vp[(kt * 64 + mi * 16 + lg * 4 + j) * NHD + f * 16 + l15];
        #pragma unroll
        for (int ni = 0; ni < 2; ++ni)
          o[f][ni] = __builtin_amdgcn_mfma_f32_16x16x16bf16_1k(vt, p[mi][ni], o[f][ni], 0, 0, 0);
      }
  }
  const float inv0 = 1.f / lstate[0], inv1 = 1.f / lstate[1];
  #pragma unroll
  for (int f = 0; f < 8; ++f)
    #pragma unroll
    for (int ni = 0; ni < 2; ++ni) {
      const float inv = ni ? inv1 : inv0;
      const int q = q0 + ni * 16 + l15;
      const int hd = f * 16 + lg * 4;
      ushortx4 ov;
      #pragma unroll
      for (int r = 0; r < 4; ++r) ov[r] = f2bf(o[f][ni][r] * inv);
      *reinterpret_cast<ushortx4*>(ctx + ((long)(b * NS + q)) * ND + h * NHD + hd) = ov;
    }
}

extern "C" void kernel_launch(void* const* d_in, const int* in_sizes, int n_in,
                              void* d_out, int out_size, void* d_ws, size_t ws_size,
                              hipStream_t stream) {
  const float* x     = (const float*)d_in[0];
  const float* w_qkv = (const float*)d_in[1];
  const float* w_o   = (const float*)d_in[2];
  char* ws = (char*)d_ws;
  if (ws_size < 369098752UL) return;
  ushort_t* xb    = (ushort_t*)(ws);
  ushort_t* wqkvb = (ushort_t*)(ws + 67108864L);
  ushort_t* wob   = (ushort_t*)(ws + 92274688L);
  ushort_t* qkvb  = (ushort_t*)(ws + 100663296L);
  ushort_t* ctxb  = (ushort_t*)(ws + 301989888L);

  const long nx = (long)NB * NS * ND;
  const long nq = 3L * ND * ND;
  const long no = (long)ND * ND;
  cast_f32_bf16<<<dim3(nx / 1024), 256, 0, stream>>>(x, xb, nx);
  cast_f32_bf16<<<dim3(nq / 1024), 256, 0, stream>>>(w_qkv, wqkvb, nq);
  cast_f32_bf16<<<dim3(no / 1024), 256, 0, stream>>>(w_o, wob, no);

  const int lds_bytes = 2 * 32768;  // 64 KiB -> 2 blocks/CU
  (void)hipFuncSetAttribute(reinterpret_cast<const void*>(&gemm256<1>),
                            hipFuncAttributeMaxDynamicSharedMemorySize, lds_bytes);
  (void)hipFuncSetAttribute(reinterpret_cast<const void*>(&gemm256<0>),
                            hipFuncAttributeMaxDynamicSharedMemorySize, lds_bytes);

  // qkv = x @ w_qkv^T  -> permuted bf16 [3][B][H][S][HD]
  gemm256<1><<<dim3(64 * 24), 512, lds_bytes, stream>>>(xb, wqkvb, nullptr, qkvb,
                                                        NB * NS, 3 * ND, ND);
  // fused causal attention -> ctx bf16 [B][S][D]
  attn_fused<<<dim3(NB * NH), 512, 0, stream>>>(qkvb, ctxb);
  // out = ctx @ w_o^T  (fp32)
  gemm256<0><<<dim3(64 * 8), 512, lds_bytes, stream>>>(ctxb, wob, (float*)d_out, nullptr,
                                                       NB * NS, ND, ND);
}

// Round 8
// 673.499 us; speedup vs baseline: 8.2071x; 8.2071x over previous
//
#include <hip/hip_runtime.h>

#define NB 64
#define NS 256
#define ND 2048
#define NH 16
#define NHD 128

typedef unsigned short ushort_t;
typedef __attribute__((ext_vector_type(8))) __bf16 bf16x8;
typedef __attribute__((ext_vector_type(4))) short shortx4;
typedef __attribute__((ext_vector_type(4))) float f32x4;
typedef __attribute__((ext_vector_type(4))) unsigned short ushortx4;

__device__ __forceinline__ unsigned short f2bf(float f) {
  union { float f; unsigned int u; } v; v.f = f;
  unsigned int r = v.u + 0x7FFFu + ((v.u >> 16) & 1u);
  return (unsigned short)(r >> 16);
}

__device__ __forceinline__ void gload16(const void* g, void* l) {
  __builtin_amdgcn_global_load_lds(
      (__attribute__((address_space(1))) void*)(void*)(g),
      (__attribute__((address_space(3))) void*)(l), 16, 0, 0);
}

__global__ void cast_f32_bf16(const float* __restrict__ in, ushort_t* __restrict__ out, long n) {
  long i = ((long)blockIdx.x * blockDim.x + threadIdx.x) * 4;
  if (i + 3 < n) {
    float4 v = *reinterpret_cast<const float4*>(in + i);
    ushortx4 o;
    o.x = f2bf(v.x); o.y = f2bf(v.y); o.z = f2bf(v.z); o.w = f2bf(v.w);
    *reinterpret_cast<ushortx4*>(out + i) = o;
  }
}

// ---------------------------------------------------------------------------
// 256x256 tile GEMM, BK=64, 8 waves (2M x 4N), 2-buffer ring (2 x 64 KiB).
// Lesson R7: unified VGPR/AGPR file -> 128-VGPR acc per wave caps us at
// 2 waves/SIMD; launch_bounds(512,4) forced spills (VGPR=64, 20GB scratch
// traffic, 10x slowdown). So occupancy is fixed; instead amortize the
// per-tile overhead (lgkm drain burst + 2 waits + barrier ~ 1300cy) over
// 2x the MFMA (64/wave at BK=64 = 2484 cy/SIMD).
// Schedule per tile (R6's functionally-verified shape, BK=64):
//   stage(t+1) -> buf^1 (8 gload16/thread; HBM latency hides under MFMA);
//   ds_read 24 frags of tile t; lgkm(0); setprio(1); 64 MFMA; setprio(0);
//   vmcnt(0) (stage landed long ago); barrier.
// T2 swizzle for 128B rows: byte ^= ((row&7)<<4); inverse-swizzled global
// source, swizzled ds_read, linear gload_lds dest (rule #21). Banks: 16
// l15-lanes -> 8 distinct 16B slots x2 = 2-way, free (m136).
// T1 bijective XCD swizzle. C[m,n] = sum_k A[m,k]*Bt[n,k].
// MODE 0: fp32 C.  MODE 1: bf16 permuted qkv [3][B][H][S][HD].
// ---------------------------------------------------------------------------
template<int MODE>
__global__ __launch_bounds__(512, 2) void gemm256(const ushort_t* __restrict__ A,
                                                  const ushort_t* __restrict__ Bt,
                                                  float* __restrict__ Cf,
                                                  ushort_t* __restrict__ Cq,
                                                  int M, int N, int K) {
  extern __shared__ char smem[];   // 2 bufs * 65536B; A at +0 (32KB), B at +32768
  const int tid = threadIdx.x;
  const int wv = tid >> 6, lane = tid & 63;
  const int l15 = lane & 15, lg = lane >> 4;
  const int wm = wv >> 2, wn = wv & 3;     // 2 x 4 wave grid; wave tile 128x64

  // T1: bijective XCD-aware block swizzle
  const int nbn = N >> 8;
  const int nwg = (M >> 8) * nbn;
  const int bid = blockIdx.x;
  const int q8 = nwg >> 3, r8 = nwg & 7;
  const int xcd = bid & 7, lin = bid >> 3;
  const int wg = (xcd < r8 ? xcd * (q8 + 1) : r8 * (q8 + 1) + (xcd - r8) * q8) + lin;
  const int m0 = (wg / nbn) << 8;
  const int n0 = (wg % nbn) << 8;

  // staging source (per-lane, pre-swizzled; LDS dest stays linear).
  // dest row = ch*64 + (tid>>3), colbyte = (tid&7)*16; logical col elems =
  // ((tid&7)*16 ^ ((row&7)<<4))/2.
  const int srow = tid >> 3;                                  // 0..63
  const int sce = ((tid & 7) * 8) ^ ((srow & 7) << 3);        // elems
  const ushort_t* pa = A  + (long)(m0 + srow) * K + sce;
  const ushort_t* pb = Bt + (long)(n0 + srow) * K + sce;

  // ds_read byte-XOR: c(kk) = (kk*64 + lg*16) ^ ((l15&7)<<4)
  const int cx = (l15 & 7) << 4;
  const int c0 = (lg * 16) ^ cx;
  const int c1 = (64 + lg * 16) ^ cx;

  f32x4 acc[8][4] = {};
  const int nkt = K >> 6;          // K=2048 -> 32 tiles

  // prologue: stage tile 0 -> buf0
  #pragma unroll
  for (int ch = 0; ch < 4; ++ch) {
    gload16(pa + (long)(ch * 64) * K, smem + ch * 8192 + wv * 1024);
    gload16(pb + (long)(ch * 64) * K, smem + 32768 + ch * 8192 + wv * 1024);
  }
  asm volatile("s_waitcnt vmcnt(0)" ::: "memory");
  __builtin_amdgcn_s_barrier();

  for (int t = 0; t < nkt; ++t) {
    const char* rb = smem + (t & 1) * 65536;
    // stage next tile first: HBM latency overlaps reads + MFMA below
    if (t + 1 < nkt) {
      char* db = smem + ((t + 1) & 1) * 65536 + wv * 1024;
      const long ko = (long)(t + 1) * 64;
      #pragma unroll
      for (int ch = 0; ch < 4; ++ch) {
        gload16(pa + (long)(ch * 64) * K + ko, db + ch * 8192);
        gload16(pb + (long)(ch * 64) * K + ko, db + 32768 + ch * 8192);
      }
    }
    bf16x8 af[8][2], bf[4][2];
    #pragma unroll
    for (int i = 0; i < 8; ++i) {
      const char* base = rb + (wm * 128 + i * 16 + l15) * 128;
      af[i][0] = *reinterpret_cast<const bf16x8*>(base + c0);
      af[i][1] = *reinterpret_cast<const bf16x8*>(base + c1);
    }
    #pragma unroll
    for (int j = 0; j < 4; ++j) {
      const char* base = rb + 32768 + (wn * 64 + j * 16 + l15) * 128;
      bf[j][0] = *reinterpret_cast<const bf16x8*>(base + c0);
      bf[j][1] = *reinterpret_cast<const bf16x8*>(base + c1);
    }
    asm volatile("s_waitcnt lgkmcnt(0)" ::: "memory");
    __builtin_amdgcn_sched_barrier(0);
    __builtin_amdgcn_s_setprio(1);
    #pragma unroll
    for (int kk = 0; kk < 2; ++kk)
      #pragma unroll
      for (int i = 0; i < 8; ++i)
        #pragma unroll
        for (int j = 0; j < 4; ++j)
          acc[i][j] = __builtin_amdgcn_mfma_f32_16x16x32_bf16(af[i][kk], bf[j][kk], acc[i][j], 0, 0, 0);
    __builtin_amdgcn_s_setprio(0);
    __builtin_amdgcn_sched_barrier(0);
    asm volatile("s_waitcnt vmcnt(0)" ::: "memory");  // next-tile stage landed
    __builtin_amdgcn_s_barrier();
  }

  // epilogue: D frag col = l15 (n), rows = lg*4 + r
  #pragma unroll
  for (int k = 0; k < 8; ++k) {
    const int mrow = m0 + wm * 128 + k * 16 + lg * 4;
    #pragma unroll
    for (int j = 0; j < 4; ++j) {
      const int n = n0 + wn * 64 + j * 16 + l15;
      #pragma unroll
      for (int r = 0; r < 4; ++r) {
        const int m = mrow + r;
        const float v = acc[k][j][r];
        if (MODE == 0) {
          Cf[(long)m * N + n] = v;
        } else {
          const int tq = n >> 11, hh = (n >> 7) & 15, hd = n & 127;
          const int b = m >> 8, s = m & 255;
          Cq[((((long)tq * NB + b) * NH + hh) * NS + s) * NHD + hd] = f2bf(v);
        }
      }
    }
  }
}

// One block per (b,h); 8 waves x 32 Q-rows. Flash-style online softmax.
// (R5 version — known-good, ~90us.)
__global__ __launch_bounds__(512) void attn_fused(const ushort_t* __restrict__ qkv,
                                                  ushort_t* __restrict__ ctx) {
  const int bh = blockIdx.x;
  const int b = bh >> 4, h = bh & 15;
  const int wave = threadIdx.x >> 6, lane = threadIdx.x & 63;
  const int l15 = lane & 15, lg = lane >> 4;
  const long head_off = ((long)(b * NH + h)) * (NS * NHD);
  const ushort_t* Qp = qkv + head_off;
  const ushort_t* Kp = qkv + (long)NB * NH * NS * NHD + head_off;
  const ushort_t* Vp = qkv + 2L * NB * NH * NS * NHD + head_off;
  const int q0 = wave * 32;

  bf16x8 qf[2][4];
  #pragma unroll
  for (int ni = 0; ni < 2; ++ni)
    #pragma unroll
    for (int kk = 0; kk < 4; ++kk)
      qf[ni][kk] = *reinterpret_cast<const bf16x8*>(Qp + (q0 + ni * 16 + l15) * NHD + kk * 32 + lg * 8);

  f32x4 o[8][2] = {};
  float mstate[2] = {-1e30f, -1e30f};
  float lstate[2] = {0.f, 0.f};
  const float scale = 0.08838834764831845f;
  const int ntiles = (q0 + 32 + 63) >> 6;

  for (int kt = 0; kt < ntiles; ++kt) {
    f32x4 st[4][2] = {};
    #pragma unroll
    for (int kk = 0; kk < 4; ++kk) {
      bf16x8 kf[4];
      #pragma unroll
      for (int mi = 0; mi < 4; ++mi)
        kf[mi] = *reinterpret_cast<const bf16x8*>(Kp + (kt * 64 + mi * 16 + l15) * NHD + kk * 32 + lg * 8);
      #pragma unroll
      for (int mi = 0; mi < 4; ++mi)
        #pragma unroll
        for (int ni = 0; ni < 2; ++ni)
          st[mi][ni] = __builtin_amdgcn_mfma_f32_16x16x32_bf16(kf[mi], qf[ni][kk], st[mi][ni], 0, 0, 0);
    }
    const bool last = (kt == ntiles - 1);
    #pragma unroll
    for (int mi = 0; mi < 4; ++mi)
      #pragma unroll
      for (int ni = 0; ni < 2; ++ni)
        #pragma unroll
        for (int r = 0; r < 4; ++r) {
          const int kc = kt * 64 + mi * 16 + lg * 4 + r;
          const int q = q0 + ni * 16 + l15;
          float v = st[mi][ni][r] * scale;
          if (last && kc > q) v = -1e30f;
          st[mi][ni][r] = v;
        }
    shortx4 p[4][2];
    #pragma unroll
    for (int ni = 0; ni < 2; ++ni) {
      float tmax = -1e30f;
      #pragma unroll
      for (int mi = 0; mi < 4; ++mi)
        #pragma unroll
        for (int r = 0; r < 4; ++r) tmax = fmaxf(tmax, st[mi][ni][r]);
      tmax = fmaxf(tmax, __shfl_xor(tmax, 16, 64));
      tmax = fmaxf(tmax, __shfl_xor(tmax, 32, 64));
      const float mnew = fmaxf(mstate[ni], tmax);
      const float alpha = __expf(mstate[ni] - mnew);
      float tsum = 0.f;
      #pragma unroll
      for (int mi = 0; mi < 4; ++mi)
        #pragma unroll
        for (int r = 0; r < 4; ++r) {
          const float pe = __expf(st[mi][ni][r] - mnew);
          st[mi][ni][r] = pe;
          tsum += pe;
        }
      tsum += __shfl_xor(tsum, 16, 64);
      tsum += __shfl_xor(tsum, 32, 64);
      lstate[ni] = lstate[ni] * alpha + tsum;
      mstate[ni] = mnew;
      #pragma unroll
      for (int f = 0; f < 8; ++f)
        #pragma unroll
        for (int r = 0; r < 4; ++r) o[f][ni][r] *= alpha;
      #pragma unroll
      for (int mi = 0; mi < 4; ++mi)
        #pragma unroll
        for (int r = 0; r < 4; ++r) p[mi][ni][r] = (short)f2bf(st[mi][ni][r]);
    }
    #pragma unroll
    for (int f = 0; f < 8; ++f)
      #pragma unroll
      for (int mi = 0; mi < 4; ++mi) {
        shortx4 vt;
        #pragma unroll
        for (int j = 0; j < 4; ++j)
          vt[j] = (short)Vp[(kt * 64 + mi * 16 + lg * 4 + j) * NHD + f * 16 + l15];
        #pragma unroll
        for (int ni = 0; ni < 2; ++ni)
          o[f][ni] = __builtin_amdgcn_mfma_f32_16x16x16bf16_1k(vt, p[mi][ni], o[f][ni], 0, 0, 0);
      }
  }
  const float inv0 = 1.f / lstate[0], inv1 = 1.f / lstate[1];
  #pragma unroll
  for (int f = 0; f < 8; ++f)
    #pragma unroll
    for (int ni = 0; ni < 2; ++ni) {
      const float inv = ni ? inv1 : inv0;
      const int q = q0 + ni * 16 + l15;
      const int hd = f * 16 + lg * 4;
      ushortx4 ov;
      #pragma unroll
      for (int r = 0; r < 4; ++r) ov[r] = f2bf(o[f][ni][r] * inv);
      *reinterpret_cast<ushortx4*>(ctx + ((long)(b * NS + q)) * ND + h * NHD + hd) = ov;
    }
}

extern "C" void kernel_launch(void* const* d_in, const int* in_sizes, int n_in,
                              void* d_out, int out_size, void* d_ws, size_t ws_size,
                              hipStream_t stream) {
  const float* x     = (const float*)d_in[0];
  const float* w_qkv = (const float*)d_in[1];
  const float* w_o   = (const float*)d_in[2];
  char* ws = (char*)d_ws;
  if (ws_size < 369098752UL) return;
  ushort_t* xb    = (ushort_t*)(ws);
  ushort_t* wqkvb = (ushort_t*)(ws + 67108864L);
  ushort_t* wob   = (ushort_t*)(ws + 92274688L);
  ushort_t* qkvb  = (ushort_t*)(ws + 100663296L);
  ushort_t* ctxb  = (ushort_t*)(ws + 301989888L);

  const long nx = (long)NB * NS * ND;
  const long nq = 3L * ND * ND;
  const long no = (long)ND * ND;
  cast_f32_bf16<<<dim3(nx / 1024), 256, 0, stream>>>(x, xb, nx);
  cast_f32_bf16<<<dim3(nq / 1024), 256, 0, stream>>>(w_qkv, wqkvb, nq);
  cast_f32_bf16<<<dim3(no / 1024), 256, 0, stream>>>(w_o, wob, no);

  const int lds_bytes = 2 * 65536;  // 128 KiB (2-buffer ring, BK=64)
  (void)hipFuncSetAttribute(reinterpret_cast<const void*>(&gemm256<1>),
                            hipFuncAttributeMaxDynamicSharedMemorySize, lds_bytes);
  (void)hipFuncSetAttribute(reinterpret_cast<const void*>(&gemm256<0>),
                            hipFuncAttributeMaxDynamicSharedMemorySize, lds_bytes);

  // qkv = x @ w_qkv^T  -> permuted bf16 [3][B][H][S][HD]
  gemm256<1><<<dim3(64 * 24), 512, lds_bytes, stream>>>(xb, wqkvb, nullptr, qkvb,
                                                        NB * NS, 3 * ND, ND);
  // fused causal attention -> ctx bf16 [B][S][D]
  attn_fused<<<dim3(NB * NH), 512, 0, stream>>>(qkvb, ctxb);
  // out = ctx @ w_o^T  (fp32)
  gemm256<0><<<dim3(64 * 8), 512, lds_bytes, stream>>>(ctxb, wob, (float*)d_out, nullptr,
                                                       NB * NS, ND, ND);
}